// Round 6
// baseline (17596.269 us; speedup 1.0000x reference)
//
#include <hip/hip_runtime.h>
#include <math.h>

#define NU 512     // hidden units
#define BT 128     // batch
#define TT 1024    // timesteps
#define ID 128     // input dim
#define OC 10      // out classes
#define GGRP 32    // row groups
#define CWG 8      // WGs per group (col slices)
#define RROW 4     // rows per group   (GGRP*RROW = 128)
#define JCOL 64    // cols per WG      (CWG*JCOL = 512)
#define THREADS 512

static constexpr float F_EPS = 0.01f;
static constexpr float F_CT  = -0.6f;   // coefficient of B^T / C^T (beta=0.8)
static constexpr float F_GAM = 0.01f;

// ws layout (u32): hx0 pairs [0,131072) | hx1 pairs [131072,262144)  (1 MB)
// Each h element is an 8B (value, epoch) pair; buffer parity t&1 holds epoch t.
// The data is its own ready flag — no inter-WG barrier exists anywhere.
// NEW (round 6): the group's 4 batch rows are split into two independent
// streams A={0,1}, B={2,3}; each step runs phase A then phase B, and each
// stream's poll loads are ISSUED mid-way through the other stream's compute,
// so the exchange round trip is hidden under compute.
#define WS_HX1 131072

// LDS (dwords): hs[4][544] skewed fp32 h rows; xs double buffer 2 x [4][160].
// Skew: (r,k) -> r*544 + k + (k>>6)*4 ; (r,i) -> r*160 + i + (i>>4)*4
#define OFF_H  0
#define OFF_X0 2176
#define OFF_X1 2816
// Pad dynamic LDS to 96 KB: forces exactly 1 WG/CU so all 256 WGs are
// co-resident -> the data-poll protocol cannot deadlock.
#define LDS_BYTES 98304

typedef float f32x4 __attribute__((ext_vector_type(4)));
typedef float f32x2 __attribute__((ext_vector_type(2)));
typedef int   i32x4 __attribute__((ext_vector_type(4)));
typedef int   i32x2 __attribute__((ext_vector_type(2)));

__global__ void init_kernel(float* ws) {
    int i = blockIdx.x * 256 + threadIdx.x;   // 65536 threads x 16B = 1 MB
    *(f32x4*)(ws + (size_t)i * 4) = (f32x4){0.f, 0.f, 0.f, 0.f};
    // zeroes both pair buffers: values 0.0 and epochs 0 (= t=0's tag)
}

__global__ __launch_bounds__(THREADS, 2)
void scan_kernel(const float* __restrict__ x, const float* __restrict__ B,
                 const float* __restrict__ C, const float* __restrict__ Ew,
                 const float* __restrict__ Eb, float* ws)
{
    extern __shared__ float sm[];
    const int tid = threadIdx.x;
    const int bid = blockIdx.x;
    const int g = bid & (GGRP - 1);   // group
    const int slice = bid >> 5;       // col slice 0..7
    const int jbase = slice * JCOL;
    const int row0 = g * RROW;

    unsigned* hx0 = (unsigned*)ws;
    unsigned* hx1 = (unsigned*)ws + WS_HX1;

    // compute mapping: wave w -> 8 cols; lane = kc*8 + jl; kc = 8-way k split
    const int lane = tid & 63;
    const int w = tid >> 6;
    const int jl = lane & 7;
    const int kc = lane >> 3;
    const int cg = jbase + w * 8 + jl;     // this thread's global column
    const int k0 = kc * 64;                // this thread's k range [k0, k0+64)

    // ---- register-resident weights (constant across all 1024 steps) ----
    f32x2 rA[32], rW[32], rE[8];
    #pragma unroll
    for (int u2 = 0; u2 < 32; ++u2) {
        #pragma unroll
        for (int p = 0; p < 2; ++p) {
            int k = k0 + 2 * u2 + p;
            float dia = (k == cg) ? F_GAM : 0.0f;
            rA[u2][p] = B[(size_t)k * NU + cg] + F_CT * B[(size_t)cg * NU + k] - dia;
            rW[u2][p] = C[(size_t)k * NU + cg] + F_CT * C[(size_t)cg * NU + k] - dia;
        }
    }
    #pragma unroll
    for (int v2 = 0; v2 < 8; ++v2) {
        rE[v2][0] = Ew[(size_t)(kc * 16 + 2 * v2) * NU + cg];
        rE[v2][1] = Ew[(size_t)(kc * 16 + 2 * v2 + 1) * NU + cg];
    }
    const float ebv = Eb[cg];

    // staging mapping: each thread polls 4 h pairs (32B) of ONE row and
    // stages 4B of x. Waves 0-3 (sr 0,1) carry stream A; waves 4-7 stream B.
    const int sr = tid >> 7;               // row 0..3
    const int sk = (tid & 127) * 4;        // h element base (4 consecutive cols)
    const int xi = tid & 127;              // x element
    const int hp = sr * 544 + sk + (sk >> 6) * 4;
    const int xp = sr * 160 + xi + (xi >> 4) * 4;
    const size_t xrow = (size_t)(row0 + sr) * TT * ID;
    const size_t pbase = ((size_t)(row0 + sr) * NU + sk) * 2;   // u32 offset of pair 0

    // prologue: stage x(0); issue stream-A polls for epoch 0 (parity 0)
    sm[OFF_X0 + xp] = x[xrow + xi];
    i32x4 pA0, pA1;          // loop-carried A-poll registers
    if (w < 4) {
        const unsigned* ps = hx0 + pbase;
        asm volatile("global_load_dwordx4 %0, %2, off sc0 sc1\n\t"
                     "global_load_dwordx4 %1, %3, off sc0 sc1"
                     : "=&v"(pA0), "=&v"(pA1)
                     : "v"(ps), "v"(ps + 4) : "memory");
    }
    __syncthreads();

    for (int t = 0; t < TT; ++t) {
        const unsigned* hxin = (t & 1) ? hx1 : hx0;
        unsigned* hxout = (t & 1) ? hx0 : hx1;
        const int xcur = (t & 1) ? OFF_X1 : OFF_X0;
        const int xnxt = (t & 1) ? OFF_X0 : OFF_X1;

        // ================= PHASE A (rows row0+0, row0+1) =================
        // Check the A-polls issued mid-phase-B of t-1 (prologue for t=0).
        // vmcnt(1): outstanding = [Astore?, Ap1, Ap2, Bstore] -> waits polls,
        // leaves the newest (B-store ack) in flight. t=0: exactly 2 polls.
        if (w < 4) {
            if (t == 0)
                asm volatile("s_waitcnt vmcnt(0)" : "+v"(pA0), "+v"(pA1) :: "memory");
            else
                asm volatile("s_waitcnt vmcnt(1)" : "+v"(pA0), "+v"(pA1) :: "memory");
            while (!(pA0[1] == t && pA0[3] == t && pA1[1] == t && pA1[3] == t)) {
                __builtin_amdgcn_s_sleep(1);
                const unsigned* ps = hxin + pbase;
                asm volatile("global_load_dwordx4 %0, %2, off sc0 sc1\n\t"
                             "global_load_dwordx4 %1, %3, off sc0 sc1\n\t"
                             "s_waitcnt vmcnt(0)"
                             : "=&v"(pA0), "=&v"(pA1)
                             : "v"(ps), "v"(ps + 4) : "memory");
            }
            f32x4 hvv;
            hvv[0] = __int_as_float(pA0[0]);
            hvv[1] = __int_as_float(pA0[2]);
            hvv[2] = __int_as_float(pA1[0]);
            hvv[3] = __int_as_float(pA1[2]);
            *(f32x4*)(sm + OFF_H + hp) = hvv;   // rows 0,1 (sr<2 here)
        }
        __syncthreads();

        // x(t+1) prefetch (all threads; consumed before the phase-B barrier)
        float xnv;
        {
            const int tn = (t + 1 < TT) ? (t + 1) : t;
            const float* xsrc = x + xrow + (size_t)tn * ID + xi;
            asm volatile("global_load_dword %0, %1, off" : "=v"(xnv) : "v"(xsrc));
        }

        i32x4 pB0, pB1;   // stream-B poll regs (issued mid-A, checked at B)
        f32x2 aA2[2], aW2[2];
        #pragma unroll
        for (int rr = 0; rr < 2; ++rr) {
            const int r = rr;                       // rows 0,1
            f32x2 z = (f32x2){0.f, 0.f};
            const float* xr = sm + xcur + r * 160 + kc * 20;
            #pragma unroll
            for (int q = 0; q < 4; ++q) {
                f32x4 xv = *(const f32x4*)(xr + q * 4);
                f32x2 xlo = __builtin_shufflevector(xv, xv, 0, 1);
                f32x2 xhi = __builtin_shufflevector(xv, xv, 2, 3);
                z = __builtin_elementwise_fma(xlo, rE[2 * q], z);
                z = __builtin_elementwise_fma(xhi, rE[2 * q + 1], z);
            }
            aA2[rr] = (f32x2){0.f, 0.f};
            aW2[rr] = z;
            const float* hr = sm + OFF_H + r * 544 + kc * 68;
            #pragma unroll
            for (int q = 0; q < 16; ++q) {
                f32x4 hv = *(const f32x4*)(hr + q * 4);
                f32x2 hlo = __builtin_shufflevector(hv, hv, 0, 1);
                f32x2 hhi = __builtin_shufflevector(hv, hv, 2, 3);
                aA2[rr] = __builtin_elementwise_fma(hlo, rA[2 * q], aA2[rr]);
                aW2[rr] = __builtin_elementwise_fma(hlo, rW[2 * q], aW2[rr]);
                aA2[rr] = __builtin_elementwise_fma(hhi, rA[2 * q + 1], aA2[rr]);
                aW2[rr] = __builtin_elementwise_fma(hhi, rW[2 * q + 1], aW2[rr]);
            }
            // mid-A: issue stream-B polls for epoch t (stored end of t-1 ->
            // ~1 phase of visibility slack; checked ~0.8 phase after issue)
            if (rr == 0 && w >= 4) {
                const unsigned* ps = hxin + pbase;
                asm volatile("global_load_dwordx4 %0, %2, off sc0 sc1\n\t"
                             "global_load_dwordx4 %1, %3, off sc0 sc1"
                             : "=&v"(pB0), "=&v"(pB1)
                             : "v"(ps), "v"(ps + 4) : "memory");
            }
        }
        {   // butterfly over kc (lane bits 3..5) + store A(t+1)
            float sA[2], sW[2];
            #pragma unroll
            for (int rr = 0; rr < 2; ++rr) {
                sA[rr] = aA2[rr][0] + aA2[rr][1];
                sW[rr] = aW2[rr][0] + aW2[rr][1];
            }
            #pragma unroll
            for (int m = 8; m <= 32; m <<= 1) {
                #pragma unroll
                for (int rr = 0; rr < 2; ++rr) {
                    sA[rr] += __shfl_xor(sA[rr], m, 64);
                    sW[rr] += __shfl_xor(sW[rr], m, 64);
                }
            }
            if (kc < 2) {
                const int r = kc;
                float hold = sm[OFF_H + r * 544 + cg + (cg >> 6) * 4];
                float hnew = hold + F_EPS * sA[r] + F_EPS * tanhf(sW[r] + ebv);
                i32x2 pv;
                pv[0] = __float_as_int(hnew);
                pv[1] = t + 1;
                unsigned* dst = hxout + ((size_t)(row0 + r) * NU + cg) * 2;
                asm volatile("global_store_dwordx2 %0, %1, off sc0 sc1"
                             :: "v"(dst), "v"(pv) : "memory");
            }
        }

        // ================= PHASE B (rows row0+2, row0+3) =================
        // Check B-polls (issued mid-A). vmcnt(1): outstanding =
        // [x, Bp1, Bp2, Astore] -> waits x+polls, leaves A-store ack.
        if (w >= 4) {
            asm volatile("s_waitcnt vmcnt(1)" : "+v"(pB0), "+v"(pB1) :: "memory");
            while (!(pB0[1] == t && pB0[3] == t && pB1[1] == t && pB1[3] == t)) {
                __builtin_amdgcn_s_sleep(1);
                const unsigned* ps = hxin + pbase;
                asm volatile("global_load_dwordx4 %0, %2, off sc0 sc1\n\t"
                             "global_load_dwordx4 %1, %3, off sc0 sc1\n\t"
                             "s_waitcnt vmcnt(0)"
                             : "=&v"(pB0), "=&v"(pB1)
                             : "v"(ps), "v"(ps + 4) : "memory");
            }
            f32x4 hvv;
            hvv[0] = __int_as_float(pB0[0]);
            hvv[1] = __int_as_float(pB0[2]);
            hvv[2] = __int_as_float(pB1[0]);
            hvv[3] = __int_as_float(pB1[2]);
            *(f32x4*)(sm + OFF_H + hp) = hvv;   // rows 2,3 (sr>=2 here)
        }
        // consume prefetched x: vmcnt(1) leaves only the newest store ack
        asm volatile("s_waitcnt vmcnt(1)" : "+v"(xnv) :: "memory");
        if (t + 1 < TT)
            sm[xnxt + xp] = xnv;
        __syncthreads();

        #pragma unroll
        for (int rr = 0; rr < 2; ++rr) {
            const int r = 2 + rr;                   // rows 2,3
            f32x2 z = (f32x2){0.f, 0.f};
            const float* xr = sm + xcur + r * 160 + kc * 20;
            #pragma unroll
            for (int q = 0; q < 4; ++q) {
                f32x4 xv = *(const f32x4*)(xr + q * 4);
                f32x2 xlo = __builtin_shufflevector(xv, xv, 0, 1);
                f32x2 xhi = __builtin_shufflevector(xv, xv, 2, 3);
                z = __builtin_elementwise_fma(xlo, rE[2 * q], z);
                z = __builtin_elementwise_fma(xhi, rE[2 * q + 1], z);
            }
            aA2[rr] = (f32x2){0.f, 0.f};
            aW2[rr] = z;
            const float* hr = sm + OFF_H + r * 544 + kc * 68;
            #pragma unroll
            for (int q = 0; q < 16; ++q) {
                f32x4 hv = *(const f32x4*)(hr + q * 4);
                f32x2 hlo = __builtin_shufflevector(hv, hv, 0, 1);
                f32x2 hhi = __builtin_shufflevector(hv, hv, 2, 3);
                aA2[rr] = __builtin_elementwise_fma(hlo, rA[2 * q], aA2[rr]);
                aW2[rr] = __builtin_elementwise_fma(hlo, rW[2 * q], aW2[rr]);
                aA2[rr] = __builtin_elementwise_fma(hhi, rA[2 * q + 1], aA2[rr]);
                aW2[rr] = __builtin_elementwise_fma(hhi, rW[2 * q + 1], aW2[rr]);
            }
            // mid-B: issue stream-A polls for epoch t+1 (stored end of
            // phase A ~1.5 phase earlier; checked ~0.8 phase after issue)
            if (rr == 0 && w < 4) {
                const unsigned* ps = hxout + pbase;    // parity t+1
                asm volatile("global_load_dwordx4 %0, %2, off sc0 sc1\n\t"
                             "global_load_dwordx4 %1, %3, off sc0 sc1"
                             : "=&v"(pA0), "=&v"(pA1)
                             : "v"(ps), "v"(ps + 4) : "memory");
            }
        }
        {   // butterfly + store B(t+1)
            float sA[2], sW[2];
            #pragma unroll
            for (int rr = 0; rr < 2; ++rr) {
                sA[rr] = aA2[rr][0] + aA2[rr][1];
                sW[rr] = aW2[rr][0] + aW2[rr][1];
            }
            #pragma unroll
            for (int m = 8; m <= 32; m <<= 1) {
                #pragma unroll
                for (int rr = 0; rr < 2; ++rr) {
                    sA[rr] += __shfl_xor(sA[rr], m, 64);
                    sW[rr] += __shfl_xor(sW[rr], m, 64);
                }
            }
            if (kc >= 2 && kc < 4) {
                const int r = kc;                   // 2 or 3
                float hold = sm[OFF_H + r * 544 + cg + (cg >> 6) * 4];
                float hnew = hold + F_EPS * sA[r - 2] + F_EPS * tanhf(sW[r - 2] + ebv);
                i32x2 pv;
                pv[0] = __float_as_int(hnew);
                pv[1] = t + 1;
                unsigned* dst = hxout + ((size_t)(row0 + r) * NU + cg) * 2;
                asm volatile("global_store_dwordx2 %0, %1, off sc0 sc1"
                             :: "v"(dst), "v"(pv) : "memory");
            }
        }
        // no trailing barrier: next phase-A publish touches only rows 0,1,
        // whose last readers finished before this iteration's phase-B barrier.
    }
}

__global__ void head_kernel(const float* __restrict__ ws, const float* __restrict__ Dw,
                            const float* __restrict__ Db, float* __restrict__ out)
{
    __shared__ float red2[32][16];
    int b = blockIdx.x;
    int tid = threadIdx.x;        // 512
    int j = tid & 15;
    int kc = tid >> 4;            // 0..31, 16 k each
    // final h: epoch TT lives in buffer parity TT&1 == 0 -> pairs at ws base
    const float* h = ws;          // value = pair[0] at u32 offset 2*(b*NU+k)
    float acc = 0.0f;
    if (j < OC) {
        for (int u = 0; u < 16; ++u) {
            int k = kc * 16 + u;
            acc += h[((size_t)b * NU + k) * 2] * Dw[(size_t)k * OC + j];
        }
    }
    red2[kc][j] = acc;
    __syncthreads();
    if (kc == 0 && j < OC) {
        float s = 0.0f;
        #pragma unroll
        for (int u = 0; u < 32; ++u) s += red2[u][j];
        out[(size_t)b * OC + j] = s + Db[j];
    }
}

extern "C" void kernel_launch(void* const* d_in, const int* in_sizes, int n_in,
                              void* d_out, int out_size, void* d_ws, size_t ws_size,
                              hipStream_t stream) {
    const float* x  = (const float*)d_in[0];
    const float* B  = (const float*)d_in[1];
    const float* C  = (const float*)d_in[2];
    const float* Ew = (const float*)d_in[3];
    const float* Eb = (const float*)d_in[4];
    const float* Dw = (const float*)d_in[5];
    const float* Db = (const float*)d_in[6];
    float* ws  = (float*)d_ws;
    float* out = (float*)d_out;

    (void)hipFuncSetAttribute((const void*)scan_kernel,
                              hipFuncAttributeMaxDynamicSharedMemorySize, LDS_BYTES);

    init_kernel<<<256, 256, 0, stream>>>(ws);
    scan_kernel<<<GGRP * CWG, THREADS, LDS_BYTES, stream>>>(x, B, C, Ew, Eb, ws);
    head_kernel<<<BT, THREADS, 0, stream>>>(ws, Dw, Db, out);
}

// Round 7
// 4256.758 us; speedup vs baseline: 4.1337x; 4.1337x over previous
//
#include <hip/hip_runtime.h>
#include <math.h>

#define NU 512     // hidden units
#define BT 128     // batch
#define TT 1024    // timesteps
#define ID 128     // input dim
#define OC 10      // out classes
#define GGRP 32    // row groups
#define CWG 8      // WGs per group (col slices)
#define RROW 4     // rows per group   (GGRP*RROW = 128)
#define JCOL 64    // cols per WG      (CWG*JCOL = 512)
#define THREADS 512

static constexpr float F_EPS = 0.01f;
static constexpr float F_CT  = -0.6f;   // coefficient of B^T / C^T (beta=0.8)
static constexpr float F_GAM = 0.01f;

// ws layout (u32): hx0 pairs [0,131072) | hx1 pairs [131072,262144)  (1 MB)
// Each h element is an 8B (value, epoch) pair; buffer parity t&1 holds epoch t.
// The data is its own ready flag — no inter-WG barrier exists (round-5 proven).
// Round 6 ERRATUM: issuing polls before the producers' store point causes a
// retry storm (FETCH 333MB->16GB, 3.3x regression) — polls stay at loop top.
#define WS_HX1 131072

// LDS (dwords): hs[4][544] skewed fp32 h rows; xs double buffer 2 x [4][160].
// Skew: (r,k) -> r*544 + k + (k>>6)*4 ; (r,i) -> r*160 + i + (i>>4)*4
#define OFF_H  0
#define OFF_X0 2176
#define OFF_X1 2816
// Pad dynamic LDS to 96 KB: forces exactly 1 WG/CU so all 256 WGs are
// co-resident -> the data-poll protocol cannot deadlock.
#define LDS_BYTES 98304

typedef float f32x4 __attribute__((ext_vector_type(4)));
typedef float f32x2 __attribute__((ext_vector_type(2)));
typedef int   i32x4 __attribute__((ext_vector_type(4)));

// xor-add on the VALU pipe (DPP), keeping shuffles OFF the saturated LDS pipe:
//   0xB1  = quad_perm[1,0,3,2]  -> xor 1
//   0x4E  = quad_perm[2,3,0,1]  -> xor 2
//   0x128 = row_ror:8           -> xor 8 within each 16-lane row
#define DPP_ADD(v, CTRL) \
    ((v) + __int_as_float(__builtin_amdgcn_update_dpp( \
        0, __float_as_int(v), CTRL, 0xF, 0xF, true)))

__global__ void init_kernel(float* ws) {
    int i = blockIdx.x * 256 + threadIdx.x;   // 65536 threads x 16B = 1 MB
    *(f32x4*)(ws + (size_t)i * 4) = (f32x4){0.f, 0.f, 0.f, 0.f};
    // zeroes both pair buffers: values 0.0 and epochs 0 (= t=0's tag)
}

__global__ __launch_bounds__(THREADS, 2)
void scan_kernel(const float* __restrict__ x, const float* __restrict__ B,
                 const float* __restrict__ C, const float* __restrict__ Ew,
                 const float* __restrict__ Eb, float* ws)
{
    extern __shared__ float sm[];
    const int tid = threadIdx.x;
    const int bid = blockIdx.x;
    const int g = bid & (GGRP - 1);   // group
    const int slice = bid >> 5;       // col slice 0..7
    const int jbase = slice * JCOL;
    const int row0 = g * RROW;

    unsigned* hx0 = (unsigned*)ws;
    unsigned* hx1 = (unsigned*)ws + WS_HX1;

    // compute mapping (round 7): 16 k-groups x 4 col-pairs per wave.
    // kc (4 bits) lives on lane bits {0,1,3,4}  -> reduce via xor 1,2,8,16
    // jl (2 bits) lives on lane bits {2,5}      -> 4 column-pairs per wave
    const int lane = tid & 63;
    const int w = tid >> 6;
    const int kc = (lane & 3) | ((lane & 0x18) >> 1);   // 0..15
    const int jl = ((lane >> 2) & 1) | ((lane >> 4) & 2); // 0..3
    const int cg0 = jbase + w * 8 + jl * 2;  // this thread's column pair {cg0, cg0+1}
    const int k0 = kc * 32;                  // k range [k0, k0+32)
    const int i0 = kc * 8;                   // input range [i0, i0+8)

    // ---- register-resident weights (constant across all 1024 steps) ----
    // 32 k x 2 cols x 2 mats = 128 floats + rE 16 — same budget as round 5.
    f32x2 rA[2][16], rW[2][16], rE[2][4];
    #pragma unroll
    for (int c = 0; c < 2; ++c) {
        const int cgc = cg0 + c;
        #pragma unroll
        for (int u2 = 0; u2 < 16; ++u2) {
            #pragma unroll
            for (int p = 0; p < 2; ++p) {
                int k = k0 + 2 * u2 + p;
                float dia = (k == cgc) ? F_GAM : 0.0f;
                rA[c][u2][p] = B[(size_t)k * NU + cgc] + F_CT * B[(size_t)cgc * NU + k] - dia;
                rW[c][u2][p] = C[(size_t)k * NU + cgc] + F_CT * C[(size_t)cgc * NU + k] - dia;
            }
        }
        #pragma unroll
        for (int p2 = 0; p2 < 4; ++p2) {
            rE[c][p2][0] = Ew[(size_t)(i0 + 2 * p2) * NU + cgc];
            rE[c][p2][1] = Ew[(size_t)(i0 + 2 * p2 + 1) * NU + cgc];
        }
    }
    f32x2 ebv;
    ebv[0] = Eb[cg0];
    ebv[1] = Eb[cg0 + 1];

    // staging mapping (unchanged from round 5): each thread polls 4 h pairs
    // (32B) of one row and stages 4B of x.
    const int sr = tid >> 7;               // row 0..3
    const int sk = (tid & 127) * 4;        // h element base (4 consecutive cols)
    const int xi = tid & 127;              // x element
    const int hp = sr * 544 + sk + (sk >> 6) * 4;
    const int xp = sr * 160 + xi + (xi >> 4) * 4;
    const size_t xrow = (size_t)(row0 + sr) * TT * ID;
    const size_t pbase = ((size_t)(row0 + sr) * NU + sk) * 2;   // u32 offset of pair 0

    // stage x for t=0
    sm[OFF_X0 + xp] = x[xrow + xi];
    __syncthreads();

    for (int t = 0; t < TT; ++t) {
        const unsigned* hxin = (t & 1) ? hx1 : hx0;
        unsigned* hxout = (t & 1) ? hx0 : hx1;
        const int xcur = (t & 1) ? OFF_X1 : OFF_X0;
        const int xnxt = (t & 1) ? OFF_X0 : OFF_X1;

        // 1. POLL own 4 (value,epoch) pairs until epoch == t (round-5 proven:
        //    issued at point of need — self-regulating, no retry storm).
        f32x4 hvv;
        {
            const unsigned* src = hxin + pbase;
            i32x4 p0, p1;
            for (;;) {
                asm volatile("global_load_dwordx4 %0, %2, off sc0 sc1\n\t"
                             "global_load_dwordx4 %1, %3, off sc0 sc1\n\t"
                             "s_waitcnt vmcnt(0)"
                             : "=&v"(p0), "=&v"(p1)
                             : "v"(src), "v"(src + 4) : "memory");
                if (p0[1] == t && p0[3] == t && p1[1] == t && p1[3] == t)
                    break;
                __builtin_amdgcn_s_sleep(1);
            }
            hvv[0] = __int_as_float(p0[0]);
            hvv[1] = __int_as_float(p0[2]);
            hvv[2] = __int_as_float(p1[0]);
            hvv[3] = __int_as_float(p1[2]);
        }

        // 2. publish h to LDS; issue x(t+1) prefetch (hidden under compute).
        //    Clamp on last iter so every wave always has exactly 1 x-load +
        //    1 h-store outstanding -> vmcnt(1) at step 7 provably waits x.
        *(f32x4*)(sm + OFF_H + hp) = hvv;
        float xnv;
        {
            const int tn = (t + 1 < TT) ? (t + 1) : t;
            const float* xsrc = x + xrow + (size_t)tn * ID + xi;
            asm volatile("global_load_dword %0, %1, off"
                         : "=v"(xnv) : "v"(xsrc));
        }
        __syncthreads();

        // 3+4. z partials and h@A / h@W partials for BOTH columns of this
        //      thread over its 32 k (weights in VGPRs). LDS reads per thread:
        //      8 b128 (x: 2) + 32 b128 (h) vs round-5's 16+64 — 2x cut.
        f32x2 aA[RROW][2], aW[RROW][2];
        #pragma unroll
        for (int r = 0; r < RROW; ++r) {
            const float* xr = sm + xcur + r * 160 + i0 + (kc >> 1) * 4;
            f32x4 xv0 = *(const f32x4*)(xr);
            f32x4 xv1 = *(const f32x4*)(xr + 4);
            f32x2 xl0 = __builtin_shufflevector(xv0, xv0, 0, 1);
            f32x2 xh0 = __builtin_shufflevector(xv0, xv0, 2, 3);
            f32x2 xl1 = __builtin_shufflevector(xv1, xv1, 0, 1);
            f32x2 xh1 = __builtin_shufflevector(xv1, xv1, 2, 3);
            #pragma unroll
            for (int c = 0; c < 2; ++c) {
                f32x2 z = (f32x2){0.f, 0.f};
                z = __builtin_elementwise_fma(xl0, rE[c][0], z);
                z = __builtin_elementwise_fma(xh0, rE[c][1], z);
                z = __builtin_elementwise_fma(xl1, rE[c][2], z);
                z = __builtin_elementwise_fma(xh1, rE[c][3], z);
                aW[r][c] = z;
                aA[r][c] = (f32x2){0.f, 0.f};
            }
            const float* hr = sm + OFF_H + r * 544 + k0 + (kc >> 1) * 4;
            #pragma unroll
            for (int q = 0; q < 8; ++q) {
                f32x4 hv = *(const f32x4*)(hr + q * 4);
                f32x2 hlo = __builtin_shufflevector(hv, hv, 0, 1);
                f32x2 hhi = __builtin_shufflevector(hv, hv, 2, 3);
                #pragma unroll
                for (int c = 0; c < 2; ++c) {
                    aA[r][c] = __builtin_elementwise_fma(hlo, rA[c][2 * q], aA[r][c]);
                    aW[r][c] = __builtin_elementwise_fma(hlo, rW[c][2 * q], aW[r][c]);
                    aA[r][c] = __builtin_elementwise_fma(hhi, rA[c][2 * q + 1], aA[r][c]);
                    aW[r][c] = __builtin_elementwise_fma(hhi, rW[c][2 * q + 1], aW[r][c]);
                }
            }
        }

        // 5. collapse f32x2 -> scalar, reduce over kc lane-bits {0,1,3,4}:
        //    xor1/xor2/xor8 on the VALU pipe (DPP), only xor16 on LDS.
        float sA[RROW][2], sW[RROW][2];
        #pragma unroll
        for (int r = 0; r < RROW; ++r)
            #pragma unroll
            for (int c = 0; c < 2; ++c) {
                sA[r][c] = aA[r][c][0] + aA[r][c][1];
                sW[r][c] = aW[r][c][0] + aW[r][c][1];
            }
        #pragma unroll
        for (int r = 0; r < RROW; ++r)
            #pragma unroll
            for (int c = 0; c < 2; ++c) {
                sA[r][c] = DPP_ADD(sA[r][c], 0xB1);
                sW[r][c] = DPP_ADD(sW[r][c], 0xB1);
            }
        #pragma unroll
        for (int r = 0; r < RROW; ++r)
            #pragma unroll
            for (int c = 0; c < 2; ++c) {
                sA[r][c] = DPP_ADD(sA[r][c], 0x4E);
                sW[r][c] = DPP_ADD(sW[r][c], 0x4E);
            }
        #pragma unroll
        for (int r = 0; r < RROW; ++r)
            #pragma unroll
            for (int c = 0; c < 2; ++c) {
                sA[r][c] = DPP_ADD(sA[r][c], 0x128);
                sW[r][c] = DPP_ADD(sW[r][c], 0x128);
            }
        #pragma unroll
        for (int r = 0; r < RROW; ++r)
            #pragma unroll
            for (int c = 0; c < 2; ++c) {
                sA[r][c] += __shfl_xor(sA[r][c], 16, 64);
                sW[r][c] += __shfl_xor(sW[r][c], 16, 64);
            }

        // 6. storers: lanes with kc<4 (lane bits {3,4}==0), r = lane&3 —
        //    16 lanes x (1 row x 2 cols); one dwordx4 = two (value,epoch)
        //    pairs, self-validating publish (coverage: 4r x 4jl x 2c x 8w).
        if ((lane & 0x18) == 0) {
            const int r = lane & 3;
            const f32x2 hold = *(const f32x2*)(sm + OFF_H + r * 544 + cg0 + (cg0 >> 6) * 4);
            float h0n = hold[0] + F_EPS * sA[r][0] + F_EPS * tanhf(sW[r][0] + ebv[0]);
            float h1n = hold[1] + F_EPS * sA[r][1] + F_EPS * tanhf(sW[r][1] + ebv[1]);
            i32x4 pv;
            pv[0] = __float_as_int(h0n);
            pv[1] = t + 1;
            pv[2] = __float_as_int(h1n);
            pv[3] = t + 1;
            unsigned* dst = hxout + ((size_t)(row0 + r) * NU + cg0) * 2;
            asm volatile("global_store_dwordx4 %0, %1, off sc0 sc1"
                         :: "v"(dst), "v"(pv) : "memory");
        }

        // 7. consume prefetched x: vmcnt(1) waits the x load (older) but NOT
        //    the h store (newer) — per wave exactly {x, store} outstanding.
        asm volatile("s_waitcnt vmcnt(1)" : "+v"(xnv) :: "memory");
        if (t + 1 < TT)
            sm[xnxt + xp] = xnv;

        __syncthreads();   // protect LDS OFF_H / x buffers for next iteration
    }
}

__global__ void head_kernel(const float* __restrict__ ws, const float* __restrict__ Dw,
                            const float* __restrict__ Db, float* __restrict__ out)
{
    __shared__ float red2[32][16];
    int b = blockIdx.x;
    int tid = threadIdx.x;        // 512
    int j = tid & 15;
    int kc = tid >> 4;            // 0..31, 16 k each
    // final h: epoch TT lives in buffer parity TT&1 == 0 -> pairs at ws base
    const float* h = ws;          // value = pair[0] at u32 offset 2*(b*NU+k)
    float acc = 0.0f;
    if (j < OC) {
        for (int u = 0; u < 16; ++u) {
            int k = kc * 16 + u;
            acc += h[((size_t)b * NU + k) * 2] * Dw[(size_t)k * OC + j];
        }
    }
    red2[kc][j] = acc;
    __syncthreads();
    if (kc == 0 && j < OC) {
        float s = 0.0f;
        #pragma unroll
        for (int u = 0; u < 32; ++u) s += red2[u][j];
        out[(size_t)b * OC + j] = s + Db[j];
    }
}

extern "C" void kernel_launch(void* const* d_in, const int* in_sizes, int n_in,
                              void* d_out, int out_size, void* d_ws, size_t ws_size,
                              hipStream_t stream) {
    const float* x  = (const float*)d_in[0];
    const float* B  = (const float*)d_in[1];
    const float* C  = (const float*)d_in[2];
    const float* Ew = (const float*)d_in[3];
    const float* Eb = (const float*)d_in[4];
    const float* Dw = (const float*)d_in[5];
    const float* Db = (const float*)d_in[6];
    float* ws  = (float*)d_ws;
    float* out = (float*)d_out;

    (void)hipFuncSetAttribute((const void*)scan_kernel,
                              hipFuncAttributeMaxDynamicSharedMemorySize, LDS_BYTES);

    init_kernel<<<256, 256, 0, stream>>>(ws);
    scan_kernel<<<GGRP * CWG, THREADS, LDS_BYTES, stream>>>(x, B, C, Ew, Eb, ws);
    head_kernel<<<BT, THREADS, 0, stream>>>(ws, Dw, Db, out);
}

// Round 8
// 3547.324 us; speedup vs baseline: 4.9604x; 1.2000x over previous
//
#include <hip/hip_runtime.h>
#include <math.h>

#define NU 512     // hidden units
#define BT 128     // batch
#define TT 1024    // timesteps
#define ID 128     // input dim
#define OC 10      // out classes
#define GGRP 32    // row groups
#define CWG 8      // WGs per group (col slices)
#define RROW 4     // rows per group   (GGRP*RROW = 128)
#define JCOL 64    // cols per WG      (CWG*JCOL = 512)
#define THREADS 512

static constexpr float F_EPS = 0.01f;
static constexpr float F_CT  = -0.6f;   // coefficient of B^T / C^T (beta=0.8)
static constexpr float F_GAM = 0.01f;

// ws layout (u32): hx0 pairs [0,131072) | hx1 pairs [131072,262144)  (1 MB)
// Each h element is an 8B (value, epoch) pair; buffer parity t&1 holds epoch t.
// The data is its own ready flag — no inter-WG barrier exists (round-5 proven).
// Round 8: the step is split into 4 ROW-PHASES. Row r is STORED at phase r of
// step t and POLLED at phase r of step t+1, with the poll ISSUED one phase
// early — every poll trails its producer's store by 3 phases (~2k cy >> RT),
// so first-check success is the steady state. NOT round-6 speculation (polls
// there had ~0 slack -> retry storm, FETCH 333MB->16GB).
#define WS_HX1 131072

// LDS (dwords): hs[4][544] skewed fp32 h rows; xs double buffer 2 x [4][160].
// Skew: (r,k) -> r*544 + k + (k>>6)*4 ; (r,i) -> r*160 + i + (i>>4)*4
#define OFF_H  0
#define OFF_X0 2176
#define OFF_X1 2816
// Pad dynamic LDS to 96 KB: forces exactly 1 WG/CU so all 256 WGs are
// co-resident -> the data-poll protocol cannot deadlock.
#define LDS_BYTES 98304

typedef float f32x4 __attribute__((ext_vector_type(4)));
typedef float f32x2 __attribute__((ext_vector_type(2)));
typedef int   i32x2 __attribute__((ext_vector_type(2)));

__global__ void init_kernel(float* ws) {
    int i = blockIdx.x * 256 + threadIdx.x;   // 65536 threads x 16B = 1 MB
    *(f32x4*)(ws + (size_t)i * 4) = (f32x4){0.f, 0.f, 0.f, 0.f};
    // zeroes both pair buffers: values 0.0 and epochs 0 (= t=0's tag)
}

// CHK: wait the poll issued last phase (vmcnt(NW) — in-order retirement
// guarantees all but the NW newest vmem ops are done), then verify epoch;
// rare-miss fallback reloads with a full drain (round-5 proven, self-regulating).
#define PH_CHECK(PP, NW, SRCP)                                               \
    asm volatile("s_waitcnt vmcnt(" #NW ")" : "+v"(PP) :: "memory");         \
    while ((PP)[1] != t) {                                                   \
        __builtin_amdgcn_s_sleep(1);                                         \
        asm volatile("global_load_dwordx2 %0, %1, off sc0 sc1\n\t"           \
                     "s_waitcnt vmcnt(0)"                                    \
                     : "=&v"(PP) : "v"(SRCP) : "memory");                    \
    }

#define PH_ISSUE(PP, SRCP)                                                   \
    asm volatile("global_load_dwordx2 %0, %1, off sc0 sc1"                   \
                 : "=&v"(PP) : "v"(SRCP) : "memory");

// Per-phase compute for row R: z from x, h@A / h@W over this thread's 64 k
// (weights in VGPRs), 3-stage butterfly over kc, lanes 0-7 store (value,t+1).
#define PH_COMPUTE(R)                                                        \
    {                                                                        \
        f32x2 z = (f32x2){0.f, 0.f};                                         \
        const float* xr = sm + xcur + (R) * 160 + kc * 20;                   \
        _Pragma("unroll")                                                    \
        for (int q = 0; q < 4; ++q) {                                        \
            f32x4 xv = *(const f32x4*)(xr + q * 4);                          \
            f32x2 xlo = __builtin_shufflevector(xv, xv, 0, 1);               \
            f32x2 xhi = __builtin_shufflevector(xv, xv, 2, 3);               \
            z = __builtin_elementwise_fma(xlo, rE[2 * q], z);                \
            z = __builtin_elementwise_fma(xhi, rE[2 * q + 1], z);            \
        }                                                                    \
        f32x2 aA = (f32x2){0.f, 0.f};                                        \
        f32x2 aW = z;                                                        \
        const float* hr = sm + OFF_H + (R) * 544 + kc * 68;                  \
        _Pragma("unroll")                                                    \
        for (int q = 0; q < 16; ++q) {                                       \
            f32x4 hv = *(const f32x4*)(hr + q * 4);                          \
            f32x2 hlo = __builtin_shufflevector(hv, hv, 0, 1);               \
            f32x2 hhi = __builtin_shufflevector(hv, hv, 2, 3);               \
            aA = __builtin_elementwise_fma(hlo, rA[2 * q], aA);              \
            aW = __builtin_elementwise_fma(hlo, rW[2 * q], aW);              \
            aA = __builtin_elementwise_fma(hhi, rA[2 * q + 1], aA);          \
            aW = __builtin_elementwise_fma(hhi, rW[2 * q + 1], aW);          \
        }                                                                    \
        float sA = aA[0] + aA[1], sW = aW[0] + aW[1];                        \
        sA += __shfl_xor(sA, 8, 64);  sW += __shfl_xor(sW, 8, 64);           \
        sA += __shfl_xor(sA, 16, 64); sW += __shfl_xor(sW, 16, 64);          \
        sA += __shfl_xor(sA, 32, 64); sW += __shfl_xor(sW, 32, 64);          \
        if (lane < 8) {                                                      \
            float hold = sm[OFF_H + (R) * 544 + cg + (cg >> 6) * 4];         \
            float hnew = hold + F_EPS * sA + F_EPS * tanhf(sW + ebv);        \
            i32x2 pv; pv[0] = __float_as_int(hnew); pv[1] = t + 1;           \
            unsigned* dst = hxout + ((size_t)(row0 + (R)) * NU + cg) * 2;    \
            asm volatile("global_store_dwordx2 %0, %1, off sc0 sc1"          \
                         :: "v"(dst), "v"(pv) : "memory");                   \
        }                                                                    \
    }

__global__ __launch_bounds__(THREADS)
__attribute__((amdgpu_waves_per_eu(2, 2)))   // occupancy is LDS-forced to 2/EU;
// pinning max=2 stops the allocator from spilling the 144 weight floats to
// chase unreachable occupancy tiers.
void scan_kernel(const float* __restrict__ x, const float* __restrict__ B,
                 const float* __restrict__ C, const float* __restrict__ Ew,
                 const float* __restrict__ Eb, float* ws)
{
    extern __shared__ float sm[];
    const int tid = threadIdx.x;
    const int bid = blockIdx.x;
    const int g = bid & (GGRP - 1);   // group
    const int slice = bid >> 5;       // col slice 0..7
    const int jbase = slice * JCOL;
    const int row0 = g * RROW;

    unsigned* hx0 = (unsigned*)ws;
    unsigned* hx1 = (unsigned*)ws + WS_HX1;

    // compute mapping (round-5 proven): wave w -> 8 cols; lane = kc*8 + jl
    const int lane = tid & 63;
    const int w = tid >> 6;
    const int jl = lane & 7;
    const int kc = lane >> 3;
    const int cg = jbase + w * 8 + jl;     // this thread's global column
    const int k0 = kc * 64;                // this thread's k range [k0, k0+64)

    // ---- register-resident weights (constant across all 1024 steps) ----
    f32x2 rA[32], rW[32], rE[8];
    #pragma unroll
    for (int u2 = 0; u2 < 32; ++u2) {
        #pragma unroll
        for (int p = 0; p < 2; ++p) {
            int k = k0 + 2 * u2 + p;
            float dia = (k == cg) ? F_GAM : 0.0f;
            rA[u2][p] = B[(size_t)k * NU + cg] + F_CT * B[(size_t)cg * NU + k] - dia;
            rW[u2][p] = C[(size_t)k * NU + cg] + F_CT * C[(size_t)cg * NU + k] - dia;
        }
    }
    #pragma unroll
    for (int v2 = 0; v2 < 8; ++v2) {
        rE[v2][0] = Ew[(size_t)(kc * 16 + 2 * v2) * NU + cg];
        rE[v2][1] = Ew[(size_t)(kc * 16 + 2 * v2 + 1) * NU + cg];
    }
    const float ebv = Eb[cg];

    // poll/publish mapping: per phase, EVERY thread polls ONE (value,epoch)
    // pair: col = tid of row (row0 + r). Publish col tid into skewed LDS.
    const int hcol = tid + (tid >> 6) * 4;
    const size_t pb0 = ((size_t)(row0 + 0) * NU + tid) * 2;
    const size_t pb1 = ((size_t)(row0 + 1) * NU + tid) * 2;
    const size_t pb2 = ((size_t)(row0 + 2) * NU + tid) * 2;
    const size_t pb3 = ((size_t)(row0 + 3) * NU + tid) * 2;

    // x staging mapping (unchanged): thread stages 1 element of row sr
    const int sr = tid >> 7;
    const int xi = tid & 127;
    const int xp = sr * 160 + xi + (xi >> 4) * 4;
    const size_t xrow = (size_t)(row0 + sr) * TT * ID;

    // prologue: stage x(0); issue + drain poll for row 0 epoch 0
    sm[OFF_X0 + xp] = x[xrow + xi];
    __syncthreads();
    i32x2 ppA, ppB;
    {
        const unsigned* p0 = hx0 + pb0;
        asm volatile("global_load_dwordx2 %0, %1, off sc0 sc1\n\t"
                     "s_waitcnt vmcnt(0)"
                     : "=&v"(ppA) : "v"(p0) : "memory");
    }

    for (int t = 0; t < TT; ++t) {
        const unsigned* hxin = (t & 1) ? hx1 : hx0;
        unsigned* hxout = (t & 1) ? hx0 : hx1;
        const int xcur = (t & 1) ? OFF_X1 : OFF_X0;
        const int xnxt = (t & 1) ? OFF_X0 : OFF_X1;
        float xnv;

        // ---------------- PHASE 0 (row 0) ----------------
        {
            const unsigned* p0 = hxin + pb0;
            PH_CHECK(ppA, 1, p0)               // newer in flight: store_3
            const unsigned* p1 = hxin + pb1;
            PH_ISSUE(ppB, p1)                  // poll row 1 (3 phases of slack)
            const int tn = (t + 1 < TT) ? (t + 1) : t;
            const float* xsrc = x + xrow + (size_t)tn * ID + xi;
            asm volatile("global_load_dword %0, %1, off" : "=v"(xnv) : "v"(xsrc));
            sm[OFF_H + 0 * 544 + hcol] = __int_as_float(ppA[0]);
            __syncthreads();
            PH_COMPUTE(0)
        }
        // ---------------- PHASE 1 (row 1) ----------------
        {
            const unsigned* p1 = hxin + pb1;
            PH_CHECK(ppB, 2, p1)               // newer: x-load, store_0
            const unsigned* p2 = hxin + pb2;
            PH_ISSUE(ppA, p2)
            sm[OFF_H + 1 * 544 + hcol] = __int_as_float(ppB[0]);
            __syncthreads();
            PH_COMPUTE(1)
        }
        // ---------------- PHASE 2 (row 2) ----------------
        {
            const unsigned* p2 = hxin + pb2;
            PH_CHECK(ppA, 1, p2)               // newer: store_1
            const unsigned* p3 = hxin + pb3;
            PH_ISSUE(ppB, p3)
            sm[OFF_H + 2 * 544 + hcol] = __int_as_float(ppA[0]);
            __syncthreads();
            PH_COMPUTE(2)
        }
        // ---------------- PHASE 3 (row 3) ----------------
        {
            const unsigned* p3 = hxin + pb3;
            PH_CHECK(ppB, 1, p3)               // newer: store_2; x older -> done
            const unsigned* p0n = hxout + pb0; // row 0 epoch t+1 (stored phase 0)
            PH_ISSUE(ppA, p0n)
            if (t + 1 < TT)
                sm[xnxt + xp] = xnv;           // covered by CHK3's vmcnt
            sm[OFF_H + 3 * 544 + hcol] = __int_as_float(ppB[0]);
            __syncthreads();
            PH_COMPUTE(3)
        }
    }
}

__global__ void head_kernel(const float* __restrict__ ws, const float* __restrict__ Dw,
                            const float* __restrict__ Db, float* __restrict__ out)
{
    __shared__ float red2[32][16];
    int b = blockIdx.x;
    int tid = threadIdx.x;        // 512
    int j = tid & 15;
    int kc = tid >> 4;            // 0..31, 16 k each
    // final h: epoch TT lives in buffer parity TT&1 == 0 -> pairs at ws base
    const float* h = ws;          // value = pair[0] at u32 offset 2*(b*NU+k)
    float acc = 0.0f;
    if (j < OC) {
        for (int u = 0; u < 16; ++u) {
            int k = kc * 16 + u;
            acc += h[((size_t)b * NU + k) * 2] * Dw[(size_t)k * OC + j];
        }
    }
    red2[kc][j] = acc;
    __syncthreads();
    if (kc == 0 && j < OC) {
        float s = 0.0f;
        #pragma unroll
        for (int u = 0; u < 32; ++u) s += red2[u][j];
        out[(size_t)b * OC + j] = s + Db[j];
    }
}

extern "C" void kernel_launch(void* const* d_in, const int* in_sizes, int n_in,
                              void* d_out, int out_size, void* d_ws, size_t ws_size,
                              hipStream_t stream) {
    const float* x  = (const float*)d_in[0];
    const float* B  = (const float*)d_in[1];
    const float* C  = (const float*)d_in[2];
    const float* Ew = (const float*)d_in[3];
    const float* Eb = (const float*)d_in[4];
    const float* Dw = (const float*)d_in[5];
    const float* Db = (const float*)d_in[6];
    float* ws  = (float*)d_ws;
    float* out = (float*)d_out;

    (void)hipFuncSetAttribute((const void*)scan_kernel,
                              hipFuncAttributeMaxDynamicSharedMemorySize, LDS_BYTES);

    init_kernel<<<256, 256, 0, stream>>>(ws);
    scan_kernel<<<GGRP * CWG, THREADS, LDS_BYTES, stream>>>(x, B, C, Ew, Eb, ws);
    head_kernel<<<BT, THREADS, 0, stream>>>(ws, Dw, Db, out);
}